// Round 7
// baseline (404.790 us; speedup 1.0000x reference)
//
#include <hip/hip_runtime.h>

// Problem constants (from reference): T=100 time steps, B=256, F=4096.
// Output: [B, T, F] float32 = 419.4 MB, ONE-HOT along t: exactly one 1.0 per
// (b,f) -> 4 MB of ones, 415 MB of zeros.
//
// History (slice = dur_us minus the harness poison-fill, which varies
// +-35 us run-to-run; raw dur_us comparisons are meaningless without it):
//  r0/r2 (slice ~140): dense compute writer. NT vs plain: neutral.
//  r1 (FAILED post-timing): x re-read throughout kernel lifetime. Lesson:
//    read inputs ONCE, at the very start of the launch (K1 below).
//  r3 (slice ~152): slab-ordered dense writer -> ordering exonerated.
//  r4 (slice ~138): table + fill-identical linear writer -> our dense
//    writers cap ~4.5 TB/s vs runtime fill 6.2 TB/s.
//  r5 (slice ~122): K1 + hipMemsetAsync(out,0) + 4-B scatter of the ones.
//  r6 (slice ~118, best, 395.8 raw): full 64-B line scatter (kills most
//    partial-line RMW).
//
// r7: scatter is still ~2x its ~11 us BW floor. Fixes, all in K2:
//  - EXACT dedup, zero races: each (b,t,L) line written by exactly ONE
//    thread (thread = line-column L, block = (b, t-half); presence bitmask
//    over t in 2x u64).
//  - ORDERED writes: each thread walks t ascending; at each step the active
//    lanes of a wave write 64-B lines of the same (b,t) row at ascending L
//    -> semi-contiguous 4-KB windows swept in address order, and both
//    halves of a 128-B TCC line are written together when both contain t.
constexpr int T  = 100;
constexpr int B  = 256;
constexpr int F  = 4096;
constexpr int F4 = F / 4;                 // float4 slots per (b,t) row = 1024
constexpr int NL = F / 16;                // 64-B line-columns per row = 256

typedef float         floatx4 __attribute__((ext_vector_type(4)));
typedef unsigned int  u32;
typedef unsigned long long u64;
typedef u32           u32x4   __attribute__((ext_vector_type(4)));

// ---------------- K1: spike-time table builder ----------------
// One thread per (b, f4): reads 16 B of x + 16 B of delays, writes one u32
// (4 packed u8 spike times, st < 100 fits u8) to ws[b*1024 + f4]. ALL input
// reads for the whole launch complete here, in the first ~4 us (r1 lesson).
__global__ __launch_bounds__(256) void build_st(
    const float* __restrict__ x,
    const float* __restrict__ delays,
    u32* __restrict__ stw)
{
    const int idx = blockIdx.x * 256 + threadIdx.x;   // 0 .. B*F4-1
    const int f4  = idx & (F4 - 1);

    const floatx4 xv = reinterpret_cast<const floatx4*>(x)[idx];
    const floatx4 dv = reinterpret_cast<const floatx4*>(delays)[f4];

    // Match numpy float32 semantics exactly: separate mul / sub / mul with
    // round-to-nearest, NO fma contraction (hipcc default -ffp-contract=fast
    // would shift st by 1 near integer boundaries). Then trunc-toward-zero
    // cast (.astype(int32)) and clip to [0, T-1]. (Bit-identical to the
    // verified r0/r2/r4/r5/r6 path.)
    auto sti = [](float xi, float di) -> u32 {
        float p  = __fmul_rn(xi, di);
        float s  = __fsub_rn(1.0f, p);
        float v  = __fmul_rn(s, 99.0f);   // (T-1) = 99
        int   st = (int)v;                // trunc toward zero
        st = st < 0 ? 0 : st;
        st = st > (T - 1) ? (T - 1) : st;
        return (u32)st;
    };

    const u32 w = sti(xv.x, dv.x)
                | (sti(xv.y, dv.y) << 8)
                | (sti(xv.z, dv.z) << 16)
                | (sti(xv.w, dv.w) << 24);
    stw[idx] = w;
}

// ---------------- K2: ordered, exact-dedup line scatter ----------------
// Grid: B * 2 blocks; block = (b, t-half). Thread tid owns line-column
// L = tid (64-B line = 16 f's). It loads its 16 spike times as one aligned
// u32x4 (wave: 4 KB contiguous, L2-resident), builds a 100-bit presence
// mask, then walks its 50 t's in ascending order writing the full 64-B
// one-hot line for each present t. Each (b,t,L) line has exactly one
// writer; lines whose t is absent stay memset-zero.
__global__ __launch_bounds__(256) void scatter_lines(
    const u32* __restrict__ stw,
    float* __restrict__ out)
{
    const int L  = threadIdx.x;                 // 0 .. 255 line-column
    const int b  = blockIdx.x >> 1;
    const int t0 = (blockIdx.x & 1) * 50;       // this block's t window

    // my line's 16 spike times (4 packed u32)
    const u32x4 tw = reinterpret_cast<const u32x4*>(stw)[b * NL + L];

    // presence bitmask over t = 0..99
    u64 mlo = 0, mhi = 0;
#pragma unroll
    for (int g = 0; g < 4; ++g) {
        const u32 tg = tw[g];
#pragma unroll
        for (int k = 0; k < 4; ++k) {
            const u32 t8 = (tg >> (8 * k)) & 255u;
            if (t8 < 64u) mlo |= 1ull << t8;
            else          mhi |= 1ull << (t8 - 64u);
        }
    }

    floatx4* base = reinterpret_cast<floatx4*>(out)
                  + (size_t)b * T * F4 + (L << 2);   // + t*F4 per line

    for (int t = t0; t < t0 + 50; ++t) {
        const bool present = (t < 64) ? ((mlo >> t) & 1ull)
                                      : ((mhi >> (t - 64)) & 1ull);
        if (present) {
            floatx4* lp = base + (size_t)t * F4;
#pragma unroll
            for (int g = 0; g < 4; ++g) {
                const u32 tg = tw[g];
                floatx4 v;
                v.x = ((int)( tg        & 255u) == t) ? 1.0f : 0.0f;
                v.y = ((int)((tg >> 8)  & 255u) == t) ? 1.0f : 0.0f;
                v.z = ((int)((tg >> 16) & 255u) == t) ? 1.0f : 0.0f;
                v.w = ((int)( tg >> 24        ) == t) ? 1.0f : 0.0f;
                lp[g] = v;
            }
        }
    }
}

// ---------------- fallback (verified r2 kernel) if ws too small ----------
__global__ __launch_bounds__(256) void spike_kernel_fb(
    const float* __restrict__ x,
    const float* __restrict__ delays,
    float* __restrict__ out)
{
    const int idx = blockIdx.x * blockDim.x + threadIdx.x;
    const int f4  = idx & (F4 - 1);
    const int b   = idx >> 10;

    const floatx4 xv = reinterpret_cast<const floatx4*>(x)[idx];
    const floatx4 dv = reinterpret_cast<const floatx4*>(delays)[f4];

    auto spike_time = [](float xi, float di) -> int {
        float p  = __fmul_rn(xi, di);
        float s  = __fsub_rn(1.0f, p);
        float v  = __fmul_rn(s, 99.0f);
        int   st = (int)v;
        st = st < 0 ? 0 : st;
        st = st > (T - 1) ? (T - 1) : st;
        return st;
    };
    const int st0 = spike_time(xv.x, dv.x);
    const int st1 = spike_time(xv.y, dv.y);
    const int st2 = spike_time(xv.z, dv.z);
    const int st3 = spike_time(xv.w, dv.w);

    floatx4* outp = reinterpret_cast<floatx4*>(out) + (size_t)b * T * F4 + f4;
#pragma unroll 4
    for (int t = 0; t < T; ++t) {
        floatx4 v;
        v.x = (t == st0) ? 1.0f : 0.0f;
        v.y = (t == st1) ? 1.0f : 0.0f;
        v.z = (t == st2) ? 1.0f : 0.0f;
        v.w = (t == st3) ? 1.0f : 0.0f;
        outp[(size_t)t * F4] = v;
    }
}

extern "C" void kernel_launch(void* const* d_in, const int* in_sizes, int n_in,
                              void* d_out, int out_size, void* d_ws, size_t ws_size,
                              hipStream_t stream)
{
    const float* x      = reinterpret_cast<const float*>(d_in[0]);   // [B, F]
    const float* delays = reinterpret_cast<const float*>(d_in[1]);   // [F]
    float* out          = reinterpret_cast<float*>(d_out);           // [B, T, F]

    const size_t needed = (size_t)B * F4 * sizeof(u32);              // 1 MB
    if (ws_size >= needed && d_ws != nullptr) {
        u32* stw = reinterpret_cast<u32*>(d_ws);
        // 1) inputs read here, at the very start of the launch (r1 lesson)
        build_st<<<B * F4 / 256, 256, 0, stream>>>(x, delays, stw);
        // 2) zero the whole output via the runtime's ~6.3 TB/s fill path
        hipMemsetAsync(out, 0, (size_t)out_size, stream);
        // 3) ordered exact-dedup full-line scatter of the one-hot lines
        scatter_lines<<<B * 2, 256, 0, stream>>>(stw, out);
    } else {
        // workspace too small: verified r2 single-kernel path
        spike_kernel_fb<<<B * F4 / 256, 256, 0, stream>>>(x, delays, out);
    }
}

// Round 8
// 394.013 us; speedup vs baseline: 1.0274x; 1.0274x over previous
//
#include <hip/hip_runtime.h>

// Problem constants (from reference): T=100 time steps, B=256, F=4096.
// Output: [B, T, F] float32 = 419.4 MB, ONE-HOT along t: exactly one 1.0 per
// (b,f) -> 4 MB of ones, 415 MB of zeros.
//
// FINAL STRUCTURE (r6, best verified: 395.8 us raw, ~118 us controllable
// slice). r7's ordered exact-dedup scatter REGRESSED (~+9 us: sparse active
// lanes + divergent 50-iter loop beat the locality gain; r6's duplicate
// stores are deduped in L2 and cost no HBM bytes). Reverted.
//
// History (slice = dur_us minus the harness poison-fill, +-35 us run-to-run):
//  r0/r2 (slice ~140): dense compute writer. NT vs plain stores: neutral.
//  r1 (FAILED post-timing): x re-read throughout kernel lifetime. Lesson:
//    read inputs ONCE, at the very start of the launch (K1 below).
//  r3 (slice ~152): slab-ordered dense writer -> write ordering exonerated.
//  r4 (slice ~138): table + fill-identical linear writer -> our dense
//    writers cap ~4.5 TB/s vs runtime fill 6.2 TB/s regardless of pattern.
//  r5 (slice ~122): K1 + hipMemsetAsync(out,0) + 4-B scatter of the ones.
//  r6 (slice ~118, BEST): full 64-B-line scatter (no partial-line RMW).
//  r7 (slice ~127): exact-dedup ordered scatter -> regression. Reverted.
//
// Floor arithmetic: memset 67 + K1 4 + scatter 15-20 + fixed graph/restore
// overhead 25-35 = 111-126 us slice. r6 sits at ~118: at the floor.
constexpr int T  = 100;
constexpr int B  = 256;
constexpr int F  = 4096;
constexpr int F4 = F / 4;                 // float4 slots per (b,t) row = 1024

typedef float        floatx4 __attribute__((ext_vector_type(4)));
typedef unsigned int u32;
typedef u32          u32x4   __attribute__((ext_vector_type(4)));

// ---------------- K1: spike-time table builder ----------------
// One thread per (b, f4): reads 16 B of x + 16 B of delays, writes one u32
// (4 packed u8 spike times, st < 100 fits u8) to ws[b*1024 + f4]. ALL input
// reads for the whole launch complete here, in the first ~4 us (r1 lesson).
__global__ __launch_bounds__(256) void build_st(
    const float* __restrict__ x,
    const float* __restrict__ delays,
    u32* __restrict__ stw)
{
    const int idx = blockIdx.x * 256 + threadIdx.x;   // 0 .. B*F4-1
    const int f4  = idx & (F4 - 1);

    const floatx4 xv = reinterpret_cast<const floatx4*>(x)[idx];
    const floatx4 dv = reinterpret_cast<const floatx4*>(delays)[f4];

    // Match numpy float32 semantics exactly: separate mul / sub / mul with
    // round-to-nearest, NO fma contraction (hipcc default -ffp-contract=fast
    // would shift st by 1 near integer boundaries). Then trunc-toward-zero
    // cast (.astype(int32)) and clip to [0, T-1]. (Bit-identical to the
    // verified r0/r2/r4/r5/r6 path.)
    auto sti = [](float xi, float di) -> u32 {
        float p  = __fmul_rn(xi, di);
        float s  = __fsub_rn(1.0f, p);
        float v  = __fmul_rn(s, 99.0f);   // (T-1) = 99
        int   st = (int)v;                // trunc toward zero
        st = st < 0 ? 0 : st;
        st = st > (T - 1) ? (T - 1) : st;
        return (u32)st;
    };

    const u32 w = sti(xv.x, dv.x)
                | (sti(xv.y, dv.y) << 8)
                | (sti(xv.z, dv.z) << 16)
                | (sti(xv.w, dv.w) << 24);
    stw[idx] = w;
}

// ---------------- K2: full-line one-hot scatter (r6, verified) ----------
// Thread (b, f4) owns 4 ones. Line column L = f4>>2 covers f = 16L..16L+15;
// its spike times are the aligned u32x4 table chunk at (b*256 + L). For each
// DISTINCT spike time among this thread's 4, write the complete 64-B line
// out[b, t, 16L..16L+15] (one-hot for all 16 f's) as 4x dwordx4 -> no
// partial-line RMW. Threads with f4 in the same group write identical bytes
// to any shared line: benign idempotent race, deterministic result; L2
// dedups the HBM write-back (~62.5 MB distinct lines).
__global__ __launch_bounds__(256) void scatter_lines(
    const u32* __restrict__ stw,
    float* __restrict__ out)
{
    const int idx = blockIdx.x * 256 + threadIdx.x;   // 0 .. B*F4-1
    const int f4  = idx & (F4 - 1);
    const int b   = idx >> 10;
    const int L   = f4 >> 2;                          // 64-B line column

    const u32   w  = stw[idx];                        // my 4 spike times
    const u32x4 tw = reinterpret_cast<const u32x4*>(stw)[idx >> 2]; // line's 16

    const int st0 =  w        & 255u;
    const int st1 = (w >> 8)  & 255u;
    const int st2 = (w >> 16) & 255u;
    const int st3 =  w >> 24;

    floatx4* base = reinterpret_cast<floatx4*>(out)
                  + ((size_t)b * T) * F4 + (L << 2);  // + t*F4 per line

    auto write_line = [&](int t) {
        floatx4* lp = base + (size_t)t * F4;
#pragma unroll
        for (int g = 0; g < 4; ++g) {
            const u32 tg = tw[g];
            floatx4 v;
            v.x = ((int)( tg        & 255u) == t) ? 1.0f : 0.0f;
            v.y = ((int)((tg >> 8)  & 255u) == t) ? 1.0f : 0.0f;
            v.z = ((int)((tg >> 16) & 255u) == t) ? 1.0f : 0.0f;
            v.w = ((int)( tg >> 24        ) == t) ? 1.0f : 0.0f;
            lp[g] = v;
        }
    };

    write_line(st0);
    if (st1 != st0)                             write_line(st1);
    if (st2 != st0 && st2 != st1)               write_line(st2);
    if (st3 != st0 && st3 != st1 && st3 != st2) write_line(st3);
}

// ---------------- fallback (verified r2 kernel) if ws too small ----------
__global__ __launch_bounds__(256) void spike_kernel_fb(
    const float* __restrict__ x,
    const float* __restrict__ delays,
    float* __restrict__ out)
{
    const int idx = blockIdx.x * blockDim.x + threadIdx.x;
    const int f4  = idx & (F4 - 1);
    const int b   = idx >> 10;

    const floatx4 xv = reinterpret_cast<const floatx4*>(x)[idx];
    const floatx4 dv = reinterpret_cast<const floatx4*>(delays)[f4];

    auto spike_time = [](float xi, float di) -> int {
        float p  = __fmul_rn(xi, di);
        float s  = __fsub_rn(1.0f, p);
        float v  = __fmul_rn(s, 99.0f);
        int   st = (int)v;
        st = st < 0 ? 0 : st;
        st = st > (T - 1) ? (T - 1) : st;
        return st;
    };
    const int st0 = spike_time(xv.x, dv.x);
    const int st1 = spike_time(xv.y, dv.y);
    const int st2 = spike_time(xv.z, dv.z);
    const int st3 = spike_time(xv.w, dv.w);

    floatx4* outp = reinterpret_cast<floatx4*>(out) + (size_t)b * T * F4 + f4;
#pragma unroll 4
    for (int t = 0; t < T; ++t) {
        floatx4 v;
        v.x = (t == st0) ? 1.0f : 0.0f;
        v.y = (t == st1) ? 1.0f : 0.0f;
        v.z = (t == st2) ? 1.0f : 0.0f;
        v.w = (t == st3) ? 1.0f : 0.0f;
        outp[(size_t)t * F4] = v;
    }
}

extern "C" void kernel_launch(void* const* d_in, const int* in_sizes, int n_in,
                              void* d_out, int out_size, void* d_ws, size_t ws_size,
                              hipStream_t stream)
{
    const float* x      = reinterpret_cast<const float*>(d_in[0]);   // [B, F]
    const float* delays = reinterpret_cast<const float*>(d_in[1]);   // [F]
    float* out          = reinterpret_cast<float*>(d_out);           // [B, T, F]

    const size_t needed = (size_t)B * F4 * sizeof(u32);              // 1 MB
    if (ws_size >= needed && d_ws != nullptr) {
        u32* stw = reinterpret_cast<u32*>(d_ws);
        // 1) inputs read here, at the very start of the launch (r1 lesson)
        build_st<<<B * F4 / 256, 256, 0, stream>>>(x, delays, stw);
        // 2) zero the whole output via the runtime's ~6.3 TB/s fill path
        hipMemsetAsync(out, 0, (size_t)out_size, stream);
        // 3) write the ~1M one-hot lines as FULL 64-B lines (no RMW)
        scatter_lines<<<B * F4 / 256, 256, 0, stream>>>(stw, out);
    } else {
        // workspace too small: verified r2 single-kernel path
        spike_kernel_fb<<<B * F4 / 256, 256, 0, stream>>>(x, delays, out);
    }
}